// Round 5
// baseline (603.208 us; speedup 1.0000x reference)
//
#include <hip/hip_runtime.h>

// Problem constants (B=2, T=4, NPTS_PER=32768, C=128, HEADS=4, HD=32)
#define NPER   32768
#define TT     4
#define CDIM   128
#define NSEQ   65536                 // b * n
#define FEAT_OUT_ELEMS (NSEQ * CDIM) // 8388608; idx region follows

constexpr int TSEQ = 8;        // sequences per block
constexpr int ROWS = TSEQ * TT; // 32 point-rows per block

// ---------------------------------------------------------------------------
// Micro-kernel: t_qkv[t][col] = temp_embed[t] @ w_qkv  (4 x 384) -> d_ws
// ---------------------------------------------------------------------------
__global__ void tqkv_kernel(const float* __restrict__ temp_embed,
                            const float* __restrict__ w_qkv,
                            float* __restrict__ tqkv) {
    int tid = blockIdx.x * blockDim.x + threadIdx.x;
    if (tid >= TT * 384) return;
    int t = tid / 384, col = tid - t * 384;
    float acc = 0.f;
#pragma unroll 8
    for (int k = 0; k < CDIM; ++k)
        acc = fmaf(temp_embed[t * CDIM + k], w_qkv[k * 384 + col], acc);
    tqkv[t * 384 + col] = acc;
}

// ---------------------------------------------------------------------------
// Fused: stage features -> KV proj (all t) -> Q proj (t=3) -> 4-wide softmax
//        -> PV -> w_out -> write feat_out row; plus idx_out gather.
// LDS ~58KB -> 2 blocks/CU.
// ---------------------------------------------------------------------------
__global__ __launch_bounds__(256, 2) void fused_kernel(
    const float* __restrict__ feat,
    const int*   __restrict__ indices,
    const float* __restrict__ w_qkv,
    const float* __restrict__ w_out,
    const float* __restrict__ tqkv,
    float* __restrict__ out) {

    __shared__ float As[ROWS][CDIM];       // 16 KB   staged feature rows
    __shared__ float KVs[ROWS][256 + 2];   // 33 KB   k: cols 0..127, v: 128..255
    __shared__ float Qs[TSEQ][CDIM + 2];   // 4.2 KB  q rows (t=3)
    __shared__ float Os[TSEQ][CDIM + 2];   // 4.2 KB  attention output rows
    __shared__ int   tix[ROWS];            // time index per row (from indices)

    const int tid  = threadIdx.x;
    const int seq0 = blockIdx.x * TSEQ;

    // ---- stage A: 32 rows x 128 f32, float4-coalesced ----
    for (int i = tid; i < ROWS * 32; i += 256) {
        int r = i >> 5, c4 = i & 31;
        int s = seq0 + (r >> 2);
        int ttr = r & 3;
        int b = s >> 15, n = s & (NPER - 1);
        int p = (b * TT + ttr) * NPER + n;      // global point row
        float4 v = *reinterpret_cast<const float4*>(feat + (size_t)p * CDIM + c4 * 4);
        *reinterpret_cast<float4*>(&As[r][c4 * 4]) = v;
        if (c4 == 0) tix[r] = indices[p * 3] & (TT - 1);  // col0 % t
    }
    __syncthreads();

    const int tx = tid & 63, ty = tid >> 6;   // ty in [0,4): row-group / wave

    // ---- KV GEMM: rows ty*8..+7, qkv-cols 128 + tx + 64c (c<4) ----
    float acc[8][4];
#pragma unroll
    for (int j = 0; j < 8; ++j)
#pragma unroll
        for (int c = 0; c < 4; ++c) acc[j][c] = 0.f;
    {
        const float* wp = w_qkv + 128 + tx;   // KV column base
#pragma unroll 4
        for (int k = 0; k < CDIM; ++k) {
            float w0 = wp[k * 384 + 0];
            float w1 = wp[k * 384 + 64];
            float w2 = wp[k * 384 + 128];
            float w3 = wp[k * 384 + 192];
#pragma unroll
            for (int j = 0; j < 8; ++j) {
                float a = As[ty * 8 + j][k];  // same addr across wave -> broadcast
                acc[j][0] = fmaf(a, w0, acc[j][0]);
                acc[j][1] = fmaf(a, w1, acc[j][1]);
                acc[j][2] = fmaf(a, w2, acc[j][2]);
                acc[j][3] = fmaf(a, w3, acc[j][3]);
            }
        }
    }
#pragma unroll
    for (int j = 0; j < 8; ++j) {
        int r = ty * 8 + j;
        int te = tix[r];
#pragma unroll
        for (int c = 0; c < 4; ++c) {
            int col = tx + 64 * c;
            KVs[r][col] = acc[j][c] + tqkv[te * 384 + 128 + col];
        }
    }

    // ---- Q GEMM (t=3 rows only): 8 rows x 128 cols ----
    float qa[2][2] = {{0.f, 0.f}, {0.f, 0.f}};
#pragma unroll 4
    for (int k = 0; k < CDIM; ++k) {
        float w0 = w_qkv[k * 384 + tx];
        float w1 = w_qkv[k * 384 + tx + 64];
        float a0 = As[(ty * 2) * 4 + 3][k];
        float a1 = As[(ty * 2 + 1) * 4 + 3][k];
        qa[0][0] = fmaf(a0, w0, qa[0][0]);
        qa[0][1] = fmaf(a0, w1, qa[0][1]);
        qa[1][0] = fmaf(a1, w0, qa[1][0]);
        qa[1][1] = fmaf(a1, w1, qa[1][1]);
    }
#pragma unroll
    for (int rr = 0; rr < 2; ++rr) {
        int ls = ty * 2 + rr;
        int te = tix[ls * 4 + 3];
        Qs[ls][tx]      = qa[rr][0] + tqkv[te * 384 + tx];
        Qs[ls][tx + 64] = qa[rr][1] + tqkv[te * 384 + tx + 64];
    }
    __syncthreads();

    // ---- attention: 32 (seq,head) pairs x 8 lanes (4 dims each) ----
    {
        const float scale = 0.17677669529663687f;  // 1/sqrt(32)
        int pr = tid >> 3, j = tid & 7;
        int ls = pr >> 2, h = pr & 3;
        int d0 = h * 32 + j * 4;
        float q0 = Qs[ls][d0], q1 = Qs[ls][d0 + 1];
        float q2 = Qs[ls][d0 + 2], q3 = Qs[ls][d0 + 3];
        float sc[4];
#pragma unroll
        for (int t2 = 0; t2 < 4; ++t2) {
            const float* kr = &KVs[ls * 4 + t2][d0];
            float sum = fmaf(q0, kr[0], fmaf(q1, kr[1], fmaf(q2, kr[2], q3 * kr[3])));
            sum += __shfl_xor(sum, 1);
            sum += __shfl_xor(sum, 2);
            sum += __shfl_xor(sum, 4);
            sc[t2] = sum * scale;
        }
        float m = fmaxf(fmaxf(sc[0], sc[1]), fmaxf(sc[2], sc[3]));
        float p[4]; float Z = 0.f;
#pragma unroll
        for (int t2 = 0; t2 < 4; ++t2) { p[t2] = expf(sc[t2] - m); Z += p[t2]; }
        float rZ = 1.f / Z;
#pragma unroll
        for (int t2 = 0; t2 < 4; ++t2) p[t2] *= rZ;
#pragma unroll
        for (int d = 0; d < 4; ++d) {
            float o = 0.f;
#pragma unroll
            for (int t2 = 0; t2 < 4; ++t2)
                o = fmaf(p[t2], KVs[ls * 4 + t2][128 + d0 + d], o);
            Os[ls][d0 + d] = o;
        }
    }
    __syncthreads();

    // ---- w_out GEMM: 8 rows x 128 cols, write feat_out ----
    float oa[2][2] = {{0.f, 0.f}, {0.f, 0.f}};
#pragma unroll 4
    for (int k = 0; k < CDIM; ++k) {
        float w0 = w_out[k * CDIM + tx];
        float w1 = w_out[k * CDIM + tx + 64];
        float a0 = Os[ty * 2][k];
        float a1 = Os[ty * 2 + 1][k];
        oa[0][0] = fmaf(a0, w0, oa[0][0]);
        oa[0][1] = fmaf(a0, w1, oa[0][1]);
        oa[1][0] = fmaf(a1, w0, oa[1][0]);
        oa[1][1] = fmaf(a1, w1, oa[1][1]);
    }
#pragma unroll
    for (int rr = 0; rr < 2; ++rr) {
        int sG = seq0 + ty * 2 + rr;
        out[(size_t)sG * CDIM + tx]      = oa[rr][0];
        out[(size_t)sG * CDIM + tx + 64] = oa[rr][1];
    }

    // ---- idx_out: [b, colx, coly] of the t=3 point, as float values ----
    if (tid < TSEQ * 3) {
        int ls = tid / 3, comp = tid - ls * 3;
        int sG = seq0 + ls;
        int b = sG >> 15, n = sG & (NPER - 1);
        int p3 = (b * TT + 3) * NPER + n;
        int val = (comp == 0) ? (indices[p3 * 3] >> 2)   // col0 // t
                              : indices[p3 * 3 + comp];
        out[FEAT_OUT_ELEMS + (size_t)sG * 3 + comp] = (float)val;
    }
}

extern "C" void kernel_launch(void* const* d_in, const int* in_sizes, int n_in,
                              void* d_out, int out_size, void* d_ws, size_t ws_size,
                              hipStream_t stream) {
    const float* feat       = (const float*)d_in[0];
    const int*   indices    = (const int*)d_in[1];
    const float* temp_embed = (const float*)d_in[2];
    const float* w_qkv      = (const float*)d_in[3];
    const float* w_out      = (const float*)d_in[4];
    float* outp = (float*)d_out;
    float* tqkv = (float*)d_ws;   // 4 x 384 f32 scratch

    hipLaunchKernelGGL(tqkv_kernel, dim3(6), dim3(256), 0, stream,
                       temp_embed, w_qkv, tqkv);
    hipLaunchKernelGGL(fused_kernel, dim3(NSEQ / TSEQ), dim3(256), 0, stream,
                       feat, indices, w_qkv, w_out, tqkv, outp);
}

// Round 8
// 417.935 us; speedup vs baseline: 1.4433x; 1.4433x over previous
//
#include <hip/hip_runtime.h>

// Problem constants (B=2, T=4, NPTS_PER=32768, C=128, HEADS=4, HD=32)
#define NPER   32768
#define TT     4
#define CDIM   128
#define NSEQ   65536                 // b * n
#define FEAT_OUT_ELEMS (NSEQ * CDIM) // idx region follows

constexpr int TSEQ = 16;          // sequences per block
constexpr int ROWS = TSEQ * TT;   // 64 point-rows per block
constexpr int KV_STRIDE = 257;    // f32 LDS strides (bank-conflict-light)
constexpr int Q_STRIDE  = 129;
constexpr int O_STRIDE  = 132;    // multiple of 4 -> rows stay 16B-aligned for b128 reads

typedef __attribute__((ext_vector_type(8))) short  short8;  // 8 bf16 = 4 VGPR (MFMA A/B frag)
typedef __attribute__((ext_vector_type(4))) float  f32x4;   // MFMA C/D frag

__device__ __forceinline__ unsigned short f2bf(float x) {   // RNE f32->bf16
    unsigned u = __float_as_uint(x);
    u = (u + 0x7FFFu + ((u >> 16) & 1u)) >> 16;
    return (unsigned short)u;
}
__device__ __forceinline__ float bf2f(unsigned short h) {
    return __uint_as_float(((unsigned)h) << 16);
}

// ---------------- d_ws layout (bytes), all recomputed every call ----------------
// 0       : tqkv f32 [4][384]            = temp_embed @ w_qkv       (6144)
// 6144    : wqkvT_hi ushort [384][128]   (transposed, bf16 hi)      (98304)
// 104448  : wqkvT_lo ushort [384][128]   (bf16 of residual)         (98304)
// 202752  : woutT_hi ushort [128][128]                              (32768)
// 235520  : woutT_lo ushort [128][128]                              (32768)
// total 268288 B

__global__ void tqkv_kernel(const float* __restrict__ temp_embed,
                            const float* __restrict__ w_qkv,
                            float* __restrict__ tqkv) {
    int tid = blockIdx.x * blockDim.x + threadIdx.x;
    if (tid >= TT * 384) return;
    int t = tid / 384, col = tid - t * 384;
    float acc = 0.f;
#pragma unroll 8
    for (int k = 0; k < CDIM; ++k)
        acc = fmaf(temp_embed[t * CDIM + k], w_qkv[k * 384 + col], acc);
    tqkv[t * 384 + col] = acc;
}

// Transpose + hi/lo bf16 split of both weight matrices. 65536 threads total.
__global__ void prep_weights(const float* __restrict__ w_qkv,
                             const float* __restrict__ w_out,
                             unsigned short* __restrict__ wkT_hi,
                             unsigned short* __restrict__ wkT_lo,
                             unsigned short* __restrict__ woT_hi,
                             unsigned short* __restrict__ woT_lo) {
    int id = blockIdx.x * 256 + threadIdx.x;
    if (id < 384 * 128) {
        int col = id >> 7, k = id & 127;           // wT[col][k]
        float x = w_qkv[k * 384 + col];
        unsigned short h = f2bf(x);
        wkT_hi[id] = h;
        wkT_lo[id] = f2bf(x - bf2f(h));
    } else {
        int j = id - 384 * 128;
        int col = j >> 7, k = j & 127;
        float x = w_out[k * CDIM + col];
        unsigned short h = f2bf(x);
        woT_hi[j] = h;
        woT_lo[j] = f2bf(x - bf2f(h));
    }
}

// ---------------------------------------------------------------------------
// MFMA fused kernel. Per block: 16 sequences (64 point-rows).
// GEMM1 (KV): [64x128] @ [128x256] ; GEMM2 (Q, t=3 rows): [16x128] @ [128x128]
// attention fp32 VALU ; GEMM3: [16x128] @ [128x128].
// All GEMMs: 3-term bf16 split (ah*bh + al*bh + ah*bl) -> ~fp32 accuracy.
// MFMA 16x16x32_bf16. D layout: col=lane&15, row=(lane>>4)*4+reg (m89).
// A layout: row=lane&15, k=8*(lane>>4)+i ; B: col=lane&15, k=8*(lane>>4)+i.
// ---------------------------------------------------------------------------
__global__ __launch_bounds__(512, 2) void fused_mfma(
    const float* __restrict__ feat,
    const int*   __restrict__ indices,
    const float* __restrict__ tqkv,
    const unsigned short* __restrict__ wkT_hi,
    const unsigned short* __restrict__ wkT_lo,
    const unsigned short* __restrict__ woT_hi,
    const unsigned short* __restrict__ woT_lo,
    float* __restrict__ out) {

    __shared__ unsigned short AsH[ROWS * CDIM];   // 16 KB, XOR-swizzled rows
    __shared__ unsigned short AsL[ROWS * CDIM];   // 16 KB
    __shared__ float KVs[ROWS * KV_STRIDE];       // 64.3 KB  k:0..127 v:128..255
    __shared__ float Qs[TSEQ * Q_STRIDE];         // 8.1 KB
    __shared__ float Os[TSEQ * O_STRIDE];         // 8.25 KB
    __shared__ int   tix[ROWS];

    const int tid  = threadIdx.x;
    const int seq0 = blockIdx.x * TSEQ;

    // ---- stage A: 64 rows x 128 f32 -> bf16 hi/lo in LDS (swizzled) ----
#pragma unroll
    for (int i = 0; i < 4; ++i) {
        int idx = tid + i * 512;                  // 2048 float4 chunks
        int row = idx >> 5, c4 = idx & 31;
        int s = seq0 + (row >> 2), t = row & 3;
        int b = s >> 15, n = s & (NPER - 1);
        size_t p = (size_t)(b * TT + t) * NPER + n;
        float4 v = *reinterpret_cast<const float4*>(feat + p * CDIM + c4 * 4);
        unsigned short h0 = f2bf(v.x), h1 = f2bf(v.y), h2 = f2bf(v.z), h3 = f2bf(v.w);
        unsigned short l0 = f2bf(v.x - bf2f(h0)), l1 = f2bf(v.y - bf2f(h1));
        unsigned short l2 = f2bf(v.z - bf2f(h2)), l3 = f2bf(v.w - bf2f(h3));
        unsigned off = (unsigned)(row * 256 + c4 * 8) ^ ((unsigned)(row & 7) << 4);
        uint2 hp; hp.x = (unsigned)h0 | ((unsigned)h1 << 16); hp.y = (unsigned)h2 | ((unsigned)h3 << 16);
        uint2 lp; lp.x = (unsigned)l0 | ((unsigned)l1 << 16); lp.y = (unsigned)l2 | ((unsigned)l3 << 16);
        *reinterpret_cast<uint2*>(reinterpret_cast<char*>(AsH) + off) = hp;
        *reinterpret_cast<uint2*>(reinterpret_cast<char*>(AsL) + off) = lp;
        if (c4 == 0) tix[row] = indices[p * 3] & (TT - 1);
    }
    __syncthreads();

    const int w  = tid >> 6, l = tid & 63;
    const int lr = l & 15,  lh = l >> 4;

    // ---- GEMM1: KV. wave w owns ntiles {2w,2w+1}, all 4 mtiles ----
    f32x4 accKV[4][2];
#pragma unroll
    for (int mt = 0; mt < 4; ++mt)
#pragma unroll
        for (int j = 0; j < 2; ++j) accKV[mt][j] = (f32x4){0.f, 0.f, 0.f, 0.f};

#pragma unroll
    for (int kt = 0; kt < 4; ++kt) {
        const int kb = kt * 32 + lh * 8;          // k element base for this lane
        const int c0 = (128 + (2 * w) * 16 + lr) * 128 + kb;
        const int c1 = c0 + 16 * 128;
        short8 B0h = *reinterpret_cast<const short8*>(wkT_hi + c0);
        short8 B0l = *reinterpret_cast<const short8*>(wkT_lo + c0);
        short8 B1h = *reinterpret_cast<const short8*>(wkT_hi + c1);
        short8 B1l = *reinterpret_cast<const short8*>(wkT_lo + c1);
#pragma unroll
        for (int mt = 0; mt < 4; ++mt) {
            int row = mt * 16 + lr;
            unsigned off = (unsigned)(row * 256 + kt * 64 + lh * 16) ^ ((unsigned)(row & 7) << 4);
            short8 Ah = *reinterpret_cast<const short8*>(reinterpret_cast<const char*>(AsH) + off);
            short8 Al = *reinterpret_cast<const short8*>(reinterpret_cast<const char*>(AsL) + off);
            accKV[mt][0] = __builtin_amdgcn_mfma_f32_16x16x32_bf16(Ah, B0h, accKV[mt][0], 0, 0, 0);
            accKV[mt][0] = __builtin_amdgcn_mfma_f32_16x16x32_bf16(Al, B0h, accKV[mt][0], 0, 0, 0);
            accKV[mt][0] = __builtin_amdgcn_mfma_f32_16x16x32_bf16(Ah, B0l, accKV[mt][0], 0, 0, 0);
            accKV[mt][1] = __builtin_amdgcn_mfma_f32_16x16x32_bf16(Ah, B1h, accKV[mt][1], 0, 0, 0);
            accKV[mt][1] = __builtin_amdgcn_mfma_f32_16x16x32_bf16(Al, B1h, accKV[mt][1], 0, 0, 0);
            accKV[mt][1] = __builtin_amdgcn_mfma_f32_16x16x32_bf16(Ah, B1l, accKV[mt][1], 0, 0, 0);
        }
    }
    // KV epilogue: D row=(lh*4+reg), col=lr within tile; + temp-embed bias
#pragma unroll
    for (int mt = 0; mt < 4; ++mt)
#pragma unroll
        for (int j = 0; j < 2; ++j) {
            int col = (2 * w + j) * 16 + lr;      // 0..255 (K then V)
#pragma unroll
            for (int r = 0; r < 4; ++r) {
                int row = mt * 16 + lh * 4 + r;
                int te  = tix[row];
                KVs[row * KV_STRIDE + col] = accKV[mt][j][r] + tqkv[te * 384 + 128 + col];
            }
        }

    // ---- GEMM2: Q (t=3 rows only; M-tile rows = the 16 sequences) ----
    f32x4 accQ = (f32x4){0.f, 0.f, 0.f, 0.f};
#pragma unroll
    for (int kt = 0; kt < 4; ++kt) {
        const int kb = kt * 32 + lh * 8;
        const int cq = (w * 16 + lr) * 128 + kb;  // Q cols 0..127
        short8 Bh = *reinterpret_cast<const short8*>(wkT_hi + cq);
        short8 Bl = *reinterpret_cast<const short8*>(wkT_lo + cq);
        int row = 4 * lr + 3;                     // t=3 row of sequence lr
        unsigned off = (unsigned)(row * 256 + kt * 64 + lh * 16) ^ ((unsigned)(row & 7) << 4);
        short8 Ah = *reinterpret_cast<const short8*>(reinterpret_cast<const char*>(AsH) + off);
        short8 Al = *reinterpret_cast<const short8*>(reinterpret_cast<const char*>(AsL) + off);
        accQ = __builtin_amdgcn_mfma_f32_16x16x32_bf16(Ah, Bh, accQ, 0, 0, 0);
        accQ = __builtin_amdgcn_mfma_f32_16x16x32_bf16(Al, Bh, accQ, 0, 0, 0);
        accQ = __builtin_amdgcn_mfma_f32_16x16x32_bf16(Ah, Bl, accQ, 0, 0, 0);
    }
#pragma unroll
    for (int r = 0; r < 4; ++r) {
        int s = lh * 4 + r, col = w * 16 + lr;
        int te = tix[4 * s + 3];
        Qs[s * Q_STRIDE + col] = accQ[r] + tqkv[te * 384 + col];
    }
    __syncthreads();

    // ---- attention: 64 (seq,head) pairs x 8 lanes (4 dims each), fp32 ----
    {
        const float scale = 0.17677669529663687f;  // 1/sqrt(32)
        int pr = tid >> 3, j = tid & 7;
        int ls = pr >> 2, h = pr & 3;
        int d0 = h * 32 + j * 4;
        const float* qp = &Qs[ls * Q_STRIDE + d0];
        float q0 = qp[0], q1 = qp[1], q2 = qp[2], q3 = qp[3];
        float sc[4];
#pragma unroll
        for (int t2 = 0; t2 < 4; ++t2) {
            const float* kr = &KVs[(ls * 4 + t2) * KV_STRIDE + d0];
            float sum = fmaf(q0, kr[0], fmaf(q1, kr[1], fmaf(q2, kr[2], q3 * kr[3])));
            sum += __shfl_xor(sum, 1);
            sum += __shfl_xor(sum, 2);
            sum += __shfl_xor(sum, 4);
            sc[t2] = sum * scale;
        }
        float m = fmaxf(fmaxf(sc[0], sc[1]), fmaxf(sc[2], sc[3]));
        float p[4]; float Z = 0.f;
#pragma unroll
        for (int t2 = 0; t2 < 4; ++t2) { p[t2] = expf(sc[t2] - m); Z += p[t2]; }
        float rZ = 1.f / Z;
#pragma unroll
        for (int t2 = 0; t2 < 4; ++t2) p[t2] *= rZ;
#pragma unroll
        for (int d = 0; d < 4; ++d) {
            float o = 0.f;
#pragma unroll
            for (int t2 = 0; t2 < 4; ++t2)
                o = fmaf(p[t2], KVs[(ls * 4 + t2) * KV_STRIDE + 128 + d0 + d], o);
            Os[ls * O_STRIDE + d0 + d] = o;
        }
    }
    __syncthreads();

    // ---- GEMM3: Os[16x128] @ w_out ; A split on the fly from f32 LDS ----
    f32x4 accO = (f32x4){0.f, 0.f, 0.f, 0.f};
#pragma unroll
    for (int kt = 0; kt < 4; ++kt) {
        const int kb = kt * 32 + lh * 8;
        const int co = (w * 16 + lr) * 128 + kb;
        short8 Bh = *reinterpret_cast<const short8*>(woT_hi + co);
        short8 Bl = *reinterpret_cast<const short8*>(woT_lo + co);
        const float* ap = &Os[lr * O_STRIDE + kb];
        float4 a01 = *reinterpret_cast<const float4*>(ap);
        float4 a23 = *reinterpret_cast<const float4*>(ap + 4);
        short8 Ah, Al;
        float av[8] = {a01.x, a01.y, a01.z, a01.w, a23.x, a23.y, a23.z, a23.w};
#pragma unroll
        for (int i = 0; i < 8; ++i) {
            unsigned short h = f2bf(av[i]);
            Ah[i] = (short)h;
            Al[i] = (short)f2bf(av[i] - bf2f(h));
        }
        accO = __builtin_amdgcn_mfma_f32_16x16x32_bf16(Ah, Bh, accO, 0, 0, 0);
        accO = __builtin_amdgcn_mfma_f32_16x16x32_bf16(Al, Bh, accO, 0, 0, 0);
        accO = __builtin_amdgcn_mfma_f32_16x16x32_bf16(Ah, Bl, accO, 0, 0, 0);
    }
#pragma unroll
    for (int r = 0; r < 4; ++r) {
        int s = lh * 4 + r, col = w * 16 + lr;
        out[(size_t)(seq0 + s) * CDIM + col] = accO[r];
    }

    // ---- idx_out: [b, colx, coly] of the t=3 point, as float values ----
    if (tid < TSEQ * 3) {
        int ls = tid / 3, comp = tid - ls * 3;
        int sG = seq0 + ls;
        int b = sG >> 15, n = sG & (NPER - 1);
        int p3 = (b * TT + 3) * NPER + n;
        int val = (comp == 0) ? (indices[p3 * 3] >> 2)   // col0 // t
                              : indices[p3 * 3 + comp];
        out[FEAT_OUT_ELEMS + (size_t)sG * 3 + comp] = (float)val;
    }
}

extern "C" void kernel_launch(void* const* d_in, const int* in_sizes, int n_in,
                              void* d_out, int out_size, void* d_ws, size_t ws_size,
                              hipStream_t stream) {
    const float* feat       = (const float*)d_in[0];
    const int*   indices    = (const int*)d_in[1];
    const float* temp_embed = (const float*)d_in[2];
    const float* w_qkv      = (const float*)d_in[3];
    const float* w_out      = (const float*)d_in[4];
    float* outp = (float*)d_out;

    char* ws = (char*)d_ws;
    float*          tqkv   = (float*)(ws);
    unsigned short* wkT_hi = (unsigned short*)(ws + 6144);
    unsigned short* wkT_lo = (unsigned short*)(ws + 104448);
    unsigned short* woT_hi = (unsigned short*)(ws + 202752);
    unsigned short* woT_lo = (unsigned short*)(ws + 235520);

    hipLaunchKernelGGL(tqkv_kernel, dim3(6), dim3(256), 0, stream,
                       temp_embed, w_qkv, tqkv);
    hipLaunchKernelGGL(prep_weights, dim3(256), dim3(256), 0, stream,
                       w_qkv, w_out, wkT_hi, wkT_lo, woT_hi, woT_lo);
    hipLaunchKernelGGL(fused_mfma, dim3(NSEQ / TSEQ), dim3(512), 0, stream,
                       feat, indices, tqkv, wkT_hi, wkT_lo, woT_hi, woT_lo, outp);
}

// Round 11
// 383.874 us; speedup vs baseline: 1.5714x; 1.0887x over previous
//
#include <hip/hip_runtime.h>

// Problem constants (B=2, T=4, NPTS_PER=32768, C=128, HEADS=4, HD=32)
#define NPER   32768
#define TT     4
#define CDIM   128
#define NSEQ   65536                 // b * n
#define FEAT_OUT_ELEMS (NSEQ * CDIM) // idx region follows

constexpr int TSEQ = 16;          // sequences per block
constexpr int ROWS = TSEQ * TT;   // 64 point-rows per block
constexpr int KV_W = 260;  // f32 words/row: 1040B -> 16B-aligned + 4-bank skew
constexpr int Q_W  = 132;  // f32 words/row: 528B  -> 16B-aligned + 4-bank skew
constexpr int O_W  = 136;  // ushort/row:    272B  -> 16B-aligned + 4-bank skew

typedef __attribute__((ext_vector_type(8))) short  short8;  // 8 bf16 (MFMA A/B frag)
typedef __attribute__((ext_vector_type(4))) float  f32x4;   // MFMA C/D frag

__device__ __forceinline__ unsigned short f2bf(float x) {   // RNE f32->bf16
    unsigned u = __float_as_uint(x);
    u = (u + 0x7FFFu + ((u >> 16) & 1u)) >> 16;
    return (unsigned short)u;
}
__device__ __forceinline__ float bf2f(unsigned short h) {
    return __uint_as_float(((unsigned)h) << 16);
}

// ---------------- d_ws layout (bytes), all recomputed every call ----------------
// 0       : tqkv f32 [4][384]
// 6144    : wqkvT_hi ushort [384][128]   (transposed, bf16 hi)
// 104448  : wqkvT_lo ushort [384][128]
// 202752  : woutT_hi ushort [128][128]
// 235520  : woutT_lo ushort [128][128]

__global__ void tqkv_kernel(const float* __restrict__ temp_embed,
                            const float* __restrict__ w_qkv,
                            float* __restrict__ tqkv) {
    int tid = blockIdx.x * blockDim.x + threadIdx.x;
    if (tid >= TT * 384) return;
    int t = tid / 384, col = tid - t * 384;
    float acc = 0.f;
#pragma unroll 8
    for (int k = 0; k < CDIM; ++k)
        acc = fmaf(temp_embed[t * CDIM + k], w_qkv[k * 384 + col], acc);
    tqkv[t * 384 + col] = acc;
}

__global__ void prep_weights(const float* __restrict__ w_qkv,
                             const float* __restrict__ w_out,
                             unsigned short* __restrict__ wkT_hi,
                             unsigned short* __restrict__ wkT_lo,
                             unsigned short* __restrict__ woT_hi,
                             unsigned short* __restrict__ woT_lo) {
    int id = blockIdx.x * 256 + threadIdx.x;
    if (id < 384 * 128) {
        int col = id >> 7, k = id & 127;           // wT[col][k]
        float x = w_qkv[k * 384 + col];
        unsigned short h = f2bf(x);
        wkT_hi[id] = h;
        wkT_lo[id] = f2bf(x - bf2f(h));
    } else {
        int j = id - 384 * 128;
        int col = j >> 7, k = j & 127;
        float x = w_out[k * CDIM + col];
        unsigned short h = f2bf(x);
        woT_hi[j] = h;
        woT_lo[j] = f2bf(x - bf2f(h));
    }
}

// ---------------------------------------------------------------------------
// 1024-thread fused kernel: 16 waves (4/SIMD), 16 sequences per block.
// GEMM1 (KV): wave w owns one 16-col ntile (qkv col 128+16w), 4 mtiles.
// GEMM2 (Q) / GEMM3 (out): waves 0-7. Attention: 16 lanes per (seq,head).
// 3-term bf16-split MFMA throughout (~fp32 accuracy, verified 0.0156 absmax).
// ---------------------------------------------------------------------------
__global__ __launch_bounds__(1024, 1) void fused_mfma(
    const float* __restrict__ feat,
    const int*   __restrict__ indices,
    const float* __restrict__ tqkv,
    const unsigned short* __restrict__ wkT_hi,
    const unsigned short* __restrict__ wkT_lo,
    const unsigned short* __restrict__ woT_hi,
    const unsigned short* __restrict__ woT_lo,
    float* __restrict__ out) {

    __shared__ unsigned short AsH[ROWS * CDIM];   // 16 KB, XOR-swizzled rows
    __shared__ unsigned short AsL[ROWS * CDIM];   // 16 KB
    __shared__ float KVs[ROWS * KV_W];            // 65 KB: k cols 0..127, v 128..255
    __shared__ float Qs[TSEQ * Q_W];              // 8.25 KB
    __shared__ unsigned short OsH[TSEQ * O_W];    // 4.25 KB (attn out, bf16 hi)
    __shared__ unsigned short OsL[TSEQ * O_W];    // 4.25 KB (bf16 residual)
    __shared__ int tix[ROWS];
    // total ~114 KB -> 1 block/CU, 16 waves

    const int tid  = threadIdx.x;
    const int seq0 = blockIdx.x * TSEQ;

    // ---- stage A: 64 rows x 128 f32 -> bf16 hi/lo in LDS (swizzled) ----
#pragma unroll
    for (int i = 0; i < 2; ++i) {
        int idx = tid + i * 1024;                 // 2048 float4 chunks
        int row = idx >> 5, c4 = idx & 31;
        int s = seq0 + (row >> 2), t = row & 3;
        int b = s >> 15, n = s & (NPER - 1);
        size_t p = (size_t)(b * TT + t) * NPER + n;
        float4 v = *reinterpret_cast<const float4*>(feat + p * CDIM + c4 * 4);
        unsigned short h0 = f2bf(v.x), h1 = f2bf(v.y), h2 = f2bf(v.z), h3 = f2bf(v.w);
        unsigned short l0 = f2bf(v.x - bf2f(h0)), l1 = f2bf(v.y - bf2f(h1));
        unsigned short l2 = f2bf(v.z - bf2f(h2)), l3 = f2bf(v.w - bf2f(h3));
        unsigned off = (unsigned)(row * 256 + c4 * 8) ^ ((unsigned)(row & 7) << 4);
        uint2 hp; hp.x = (unsigned)h0 | ((unsigned)h1 << 16); hp.y = (unsigned)h2 | ((unsigned)h3 << 16);
        uint2 lp; lp.x = (unsigned)l0 | ((unsigned)l1 << 16); lp.y = (unsigned)l2 | ((unsigned)l3 << 16);
        *reinterpret_cast<uint2*>(reinterpret_cast<char*>(AsH) + off) = hp;
        *reinterpret_cast<uint2*>(reinterpret_cast<char*>(AsL) + off) = lp;
        if (c4 == 0) tix[row] = indices[p * 3] & (TT - 1);
    }
    __syncthreads();

    const int w  = tid >> 6, l = tid & 63;
    const int lr = l & 15,  lh = l >> 4;

    // ---- GEMM1: KV. wave w owns ntile w (kv col base 16w), 4 mtiles ----
    f32x4 acc[4];
#pragma unroll
    for (int mt = 0; mt < 4; ++mt) acc[mt] = (f32x4){0.f, 0.f, 0.f, 0.f};
#pragma unroll
    for (int kt = 0; kt < 4; ++kt) {
        const int kb = kt * 32 + lh * 8;
        const int c0 = (128 + w * 16 + lr) * 128 + kb;
        short8 Bh = *reinterpret_cast<const short8*>(wkT_hi + c0);
        short8 Bl = *reinterpret_cast<const short8*>(wkT_lo + c0);
#pragma unroll
        for (int mt = 0; mt < 4; ++mt) {
            int row = mt * 16 + lr;
            unsigned off = (unsigned)(row * 256 + kt * 64 + lh * 16) ^ ((unsigned)(row & 7) << 4);
            short8 Ah = *reinterpret_cast<const short8*>(reinterpret_cast<const char*>(AsH) + off);
            short8 Al = *reinterpret_cast<const short8*>(reinterpret_cast<const char*>(AsL) + off);
            acc[mt] = __builtin_amdgcn_mfma_f32_16x16x32_bf16(Ah, Bh, acc[mt], 0, 0, 0);
            acc[mt] = __builtin_amdgcn_mfma_f32_16x16x32_bf16(Al, Bh, acc[mt], 0, 0, 0);
            acc[mt] = __builtin_amdgcn_mfma_f32_16x16x32_bf16(Ah, Bl, acc[mt], 0, 0, 0);
        }
    }

    // ---- GEMM2: Q (t=3 rows), waves 0-7 own col-tile w ----
    f32x4 accQ = (f32x4){0.f, 0.f, 0.f, 0.f};
    if (w < 8) {
#pragma unroll
        for (int kt = 0; kt < 4; ++kt) {
            const int kb = kt * 32 + lh * 8;
            const int cq = (w * 16 + lr) * 128 + kb;
            short8 Bh = *reinterpret_cast<const short8*>(wkT_hi + cq);
            short8 Bl = *reinterpret_cast<const short8*>(wkT_lo + cq);
            int row = 4 * lr + 3;
            unsigned off = (unsigned)(row * 256 + kt * 64 + lh * 16) ^ ((unsigned)(row & 7) << 4);
            short8 Ah = *reinterpret_cast<const short8*>(reinterpret_cast<const char*>(AsH) + off);
            short8 Al = *reinterpret_cast<const short8*>(reinterpret_cast<const char*>(AsL) + off);
            accQ = __builtin_amdgcn_mfma_f32_16x16x32_bf16(Ah, Bh, accQ, 0, 0, 0);
            accQ = __builtin_amdgcn_mfma_f32_16x16x32_bf16(Al, Bh, accQ, 0, 0, 0);
            accQ = __builtin_amdgcn_mfma_f32_16x16x32_bf16(Ah, Bl, accQ, 0, 0, 0);
        }
    }

    // ---- epilogues (KVs/Qs don't alias As -> no barrier needed before) ----
#pragma unroll
    for (int mt = 0; mt < 4; ++mt) {
        int col = w * 16 + lr;                    // kv col 0..255
#pragma unroll
        for (int r = 0; r < 4; ++r) {
            int row = mt * 16 + lh * 4 + r;
            int te  = tix[row];
            KVs[row * KV_W + col] = acc[mt][r] + tqkv[te * 384 + 128 + col];
        }
    }
    if (w < 8) {
#pragma unroll
        for (int r = 0; r < 4; ++r) {
            int s = lh * 4 + r, col = w * 16 + lr;
            int te = tix[4 * s + 3];
            Qs[s * Q_W + col] = accQ[r] + tqkv[te * 384 + col];
        }
    }
    __syncthreads();

    // ---- attention: 64 (seq,head) x 16 lanes (2 dims each), fp32 ----
    {
        const float scale = 0.17677669529663687f;  // 1/sqrt(32)
        int pr = tid >> 4, j = tid & 15;
        int ls = pr >> 2, h = pr & 3;
        int d0 = h * 32 + j * 2;
        float2 qv = *reinterpret_cast<const float2*>(&Qs[ls * Q_W + d0]);
        float sc[4];
#pragma unroll
        for (int t2 = 0; t2 < 4; ++t2) {
            float2 kv = *reinterpret_cast<const float2*>(&KVs[(ls * 4 + t2) * KV_W + d0]);
            float sum = fmaf(qv.x, kv.x, qv.y * kv.y);
            sum += __shfl_xor(sum, 1);
            sum += __shfl_xor(sum, 2);
            sum += __shfl_xor(sum, 4);
            sum += __shfl_xor(sum, 8);
            sc[t2] = sum * scale;
        }
        float m = fmaxf(fmaxf(sc[0], sc[1]), fmaxf(sc[2], sc[3]));
        float p[4]; float Z = 0.f;
#pragma unroll
        for (int t2 = 0; t2 < 4; ++t2) { p[t2] = expf(sc[t2] - m); Z += p[t2]; }
        float rZ = 1.f / Z;
        float o0 = 0.f, o1 = 0.f;
#pragma unroll
        for (int t2 = 0; t2 < 4; ++t2) {
            float2 vv = *reinterpret_cast<const float2*>(&KVs[(ls * 4 + t2) * KV_W + 128 + d0]);
            float pp = p[t2] * rZ;
            o0 = fmaf(pp, vv.x, o0);
            o1 = fmaf(pp, vv.y, o1);
        }
        unsigned short h0 = f2bf(o0), h1 = f2bf(o1);
        unsigned short g0 = f2bf(o0 - bf2f(h0)), g1 = f2bf(o1 - bf2f(h1));
        *reinterpret_cast<unsigned*>(&OsH[ls * O_W + d0]) = (unsigned)h0 | ((unsigned)h1 << 16);
        *reinterpret_cast<unsigned*>(&OsL[ls * O_W + d0]) = (unsigned)g0 | ((unsigned)g1 << 16);
    }
    __syncthreads();

    // ---- GEMM3: Os[16x128] @ w_out, waves 0-7; A already split in LDS ----
    if (w < 8) {
        f32x4 accO = (f32x4){0.f, 0.f, 0.f, 0.f};
#pragma unroll
        for (int kt = 0; kt < 4; ++kt) {
            const int kb = kt * 32 + lh * 8;
            const int co = (w * 16 + lr) * 128 + kb;
            short8 Bh = *reinterpret_cast<const short8*>(woT_hi + co);
            short8 Bl = *reinterpret_cast<const short8*>(woT_lo + co);
            short8 Ah = *reinterpret_cast<const short8*>(&OsH[lr * O_W + kb]);
            short8 Al = *reinterpret_cast<const short8*>(&OsL[lr * O_W + kb]);
            accO = __builtin_amdgcn_mfma_f32_16x16x32_bf16(Ah, Bh, accO, 0, 0, 0);
            accO = __builtin_amdgcn_mfma_f32_16x16x32_bf16(Al, Bh, accO, 0, 0, 0);
            accO = __builtin_amdgcn_mfma_f32_16x16x32_bf16(Ah, Bl, accO, 0, 0, 0);
        }
#pragma unroll
        for (int r = 0; r < 4; ++r) {
            int s = lh * 4 + r, col = w * 16 + lr;
            out[(size_t)(seq0 + s) * CDIM + col] = accO[r];
        }
    }

    // ---- idx_out: [b, colx, coly] of the t=3 point, as float values ----
    if (tid < TSEQ * 3) {
        int ls = tid / 3, comp = tid - ls * 3;
        int sG = seq0 + ls;
        int b = sG >> 15, n = sG & (NPER - 1);
        int p3 = (b * TT + 3) * NPER + n;
        int val = (comp == 0) ? (indices[p3 * 3] >> 2)   // col0 // t
                              : indices[p3 * 3 + comp];
        out[FEAT_OUT_ELEMS + (size_t)sG * 3 + comp] = (float)val;
    }
}

extern "C" void kernel_launch(void* const* d_in, const int* in_sizes, int n_in,
                              void* d_out, int out_size, void* d_ws, size_t ws_size,
                              hipStream_t stream) {
    const float* feat       = (const float*)d_in[0];
    const int*   indices    = (const int*)d_in[1];
    const float* temp_embed = (const float*)d_in[2];
    const float* w_qkv      = (const float*)d_in[3];
    const float* w_out      = (const float*)d_in[4];
    float* outp = (float*)d_out;

    char* ws = (char*)d_ws;
    float*          tqkv   = (float*)(ws);
    unsigned short* wkT_hi = (unsigned short*)(ws + 6144);
    unsigned short* wkT_lo = (unsigned short*)(ws + 104448);
    unsigned short* woT_hi = (unsigned short*)(ws + 202752);
    unsigned short* woT_lo = (unsigned short*)(ws + 235520);

    hipLaunchKernelGGL(tqkv_kernel, dim3(6), dim3(256), 0, stream,
                       temp_embed, w_qkv, tqkv);
    hipLaunchKernelGGL(prep_weights, dim3(256), dim3(256), 0, stream,
                       w_qkv, w_out, wkT_hi, wkT_lo, woT_hi, woT_lo);
    hipLaunchKernelGGL(fused_mfma, dim3(NSEQ / TSEQ), dim3(1024), 0, stream,
                       feat, indices, tqkv, wkT_hi, wkT_lo, woT_hi, woT_lo, outp);
}